// Round 3
// baseline (300.094 us; speedup 1.0000x reference)
//
#include <hip/hip_runtime.h>
#include <math.h>

constexpr int kB = 256;      // batches
constexpr int kT = 261;      // tokens per batch
constexpr int kD = 768;      // dim
constexpr int kC = 5;        // cue tokens
constexpr int kG = 16;       // patch grid
constexpr int kP = 256;      // patches per batch
constexpr int kTok = kT * kD;
constexpr float kTau = 0.03f;   // fp32 screening gap threshold (est. sim err < 2e-3)

// ---------------- ws layout (bytes) ----------------
// G64   : 768*768*8 = 4,718,592   @ 0
// bw64  : 768*8     =     6,144   @ 4,718,592
// G32   : 768*768*4 = 2,359,296   @ 4,724,736
// bw32  : 768*4     =     3,072   @ 7,084,032
// u_all : 1280*768*4 = 3,932,160  @ 7,087,104
// roi   : 1280*768*4 = 3,932,160  @ 11,019,264
// total 14,951,424 bytes

// ============ K1: G = W^T W (fp64 + fp32), bw = b·W ============
__global__ __launch_bounds__(256)
void k1_gram(const float* __restrict__ W, const float* __restrict__ bvec,
             double* __restrict__ G64, float* __restrict__ G32,
             double* __restrict__ bw64, float* __restrict__ bw32)
{
    const int blk = blockIdx.x;
    const int t = threadIdx.x;
    if (blk >= 576) {                       // bw blocks (3 x 256 = 768 i's)
        const int i = (blk - 576) * 256 + t;
        double acc = 0.0;
        for (int j = 0; j < kD; ++j)
            acc += (double)bvec[j] * (double)W[(size_t)j * kD + i];   // coalesced over i
        bw64[i] = acc; bw32[i] = (float)acc;
        return;
    }
    __shared__ alignas(16) double Sd[64][34];   // [j][d-local], stride 34 (even, 16B-aligned pairs)
    __shared__ alignas(16) double Si[64][34];
    const int dt = (blk / 24) * 32, it = (blk % 24) * 32;
    const int tx = t & 15, ty = t >> 4;
    double a00 = 0, a01 = 0, a10 = 0, a11 = 0;
    const int r = t >> 2, q = t & 3;            // staging: row r (0..63), col-group q (8 floats)
    for (int jc = 0; jc < kD; jc += 64) {
        __syncthreads();
        {   // stage W[jc+r][dt + q*8 ..] and W[jc+r][it + q*8 ..] as fp64
            const float4 f0 = *(const float4*)&W[(size_t)(jc + r) * kD + dt + q * 8];
            const float4 f1 = *(const float4*)&W[(size_t)(jc + r) * kD + dt + q * 8 + 4];
            double2* dst = (double2*)&Sd[r][q * 8];
            dst[0] = make_double2((double)f0.x, (double)f0.y);
            dst[1] = make_double2((double)f0.z, (double)f0.w);
            dst[2] = make_double2((double)f1.x, (double)f1.y);
            dst[3] = make_double2((double)f1.z, (double)f1.w);
            const float4 g0 = *(const float4*)&W[(size_t)(jc + r) * kD + it + q * 8];
            const float4 g1 = *(const float4*)&W[(size_t)(jc + r) * kD + it + q * 8 + 4];
            double2* dsi = (double2*)&Si[r][q * 8];
            dsi[0] = make_double2((double)g0.x, (double)g0.y);
            dsi[1] = make_double2((double)g0.z, (double)g0.w);
            dsi[2] = make_double2((double)g1.x, (double)g1.y);
            dsi[3] = make_double2((double)g1.z, (double)g1.w);
        }
        __syncthreads();
        #pragma unroll 8
        for (int j = 0; j < 64; ++j) {
            const double2 dv = *(const double2*)&Sd[j][ty * 2];
            const double2 iv = *(const double2*)&Si[j][tx * 2];
            a00 += dv.x * iv.x; a01 += dv.x * iv.y;
            a10 += dv.y * iv.x; a11 += dv.y * iv.y;
        }
    }
    const int d0 = dt + ty * 2, i0 = it + tx * 2;
    G64[(size_t)d0 * kD + i0]           = a00;
    G64[(size_t)d0 * kD + i0 + 1]       = a01;
    G64[(size_t)(d0 + 1) * kD + i0]     = a10;
    G64[(size_t)(d0 + 1) * kD + i0 + 1] = a11;
    G32[(size_t)d0 * kD + i0]           = (float)a00;
    G32[(size_t)d0 * kD + i0 + 1]       = (float)a01;
    G32[(size_t)(d0 + 1) * kD + i0]     = (float)a10;
    G32[(size_t)(d0 + 1) * kD + i0 + 1] = (float)a11;
}

// ============ K2/K4: tiled fp32 GEMM, C = A·B (+bias) ============
// mode 0: A = cues (gathered from tokens), N-tiles 0..23 -> W^T part (tcb -> out rows c),
//         N-tiles 24..47 -> G32 part (u -> u_all). mode 1: A = roi (dense), W^T part -> out rows 5+c.
__global__ __launch_bounds__(256)
void k2_gemm(const int mode,
             const float* __restrict__ tokens, const float* __restrict__ W,
             const float* __restrict__ G32, const float* __restrict__ bvec,
             const float* __restrict__ bw32, const float* __restrict__ roi,
             float* __restrict__ u_all, float* __restrict__ out)
{
    __shared__ alignas(16) float As[64][36];   // [m-local][k]
    __shared__ alignas(16) float Bs[32][36];   // [k][n-local]
    const int mt = blockIdx.x, nt = blockIdx.y;
    const int t = threadIdx.x, tx = t & 15, ty = t >> 4;
    const bool gpart = (mode == 0) && (nt >= 24);
    const int n0tile = gpart ? (nt - 24) * 32 : nt * 32;
    float acc[4][2] = {};
    const int ar = t >> 2, aq = t & 3;          // A staging: row(64), col-group(8)
    const int br = t >> 3, bq = t & 7;          // B staging: row(32), col-group(4)
    const int am = mt * 64 + ar;
    const size_t arow = (mode == 0)
        ? ((size_t)(am / 5) * kTok + (size_t)(am % 5) * kD)
        : ((size_t)am * kD);
    const float* __restrict__ Aptr = (mode == 0) ? tokens : roi;

    for (int kc = 0; kc < kD; kc += 32) {
        __syncthreads();
        {   // stage A 64x32 (coalesced row segments)
            const float4 f0 = *(const float4*)&Aptr[arow + kc + aq * 8];
            const float4 f1 = *(const float4*)&Aptr[arow + kc + aq * 8 + 4];
            *(float4*)&As[ar][aq * 8]     = f0;
            *(float4*)&As[ar][aq * 8 + 4] = f1;
        }
        if (gpart) {        // B = G32[k][n]: rows k contiguous in n -> direct
            const float4 g = *(const float4*)&G32[(size_t)(kc + br) * kD + n0tile + bq * 4];
            *(float4*)&Bs[br][bq * 4] = g;
        } else {            // B = W^T: load W rows (n), transpose into [k][n]
            const float4 w = *(const float4*)&W[(size_t)(n0tile + br) * kD + kc + bq * 4];
            Bs[bq * 4 + 0][br] = w.x;
            Bs[bq * 4 + 1][br] = w.y;
            Bs[bq * 4 + 2][br] = w.z;
            Bs[bq * 4 + 3][br] = w.w;
        }
        __syncthreads();
        #pragma unroll
        for (int kk = 0; kk < 8; ++kk) {
            float2 bfr[4];
            #pragma unroll
            for (int e = 0; e < 4; ++e)
                bfr[e] = *(const float2*)&Bs[kk * 4 + e][tx * 2];
            #pragma unroll
            for (int mi = 0; mi < 4; ++mi) {
                const float4 av = *(const float4*)&As[ty * 4 + mi][kk * 4];
                acc[mi][0] += av.x * bfr[0].x + av.y * bfr[1].x + av.z * bfr[2].x + av.w * bfr[3].x;
                acc[mi][1] += av.x * bfr[0].y + av.y * bfr[1].y + av.z * bfr[2].y + av.w * bfr[3].y;
            }
        }
    }
    const int n0 = n0tile + tx * 2;
    #pragma unroll
    for (int mi = 0; mi < 4; ++mi) {
        const int m = mt * 64 + ty * 4 + mi;
        float2 res;
        if (gpart) {
            res.x = acc[mi][0] + bw32[n0];
            res.y = acc[mi][1] + bw32[n0 + 1];
            *(float2*)&u_all[(size_t)m * kD + n0] = res;
        } else {
            res.x = acc[mi][0] + bvec[n0];
            res.y = acc[mi][1] + bvec[n0 + 1];
            const int orow = (m / 5) * 10 + ((mode == 0) ? (m % 5) : (5 + m % 5));
            *(float2*)&out[(size_t)orow * kD + n0] = res;
        }
    }
}

// ============ K3: per-batch sims (fp32 screen) + top2 + fp64 recheck + ROI ============
__global__ __launch_bounds__(768, 1)
void k3_batch(const float* __restrict__ tokens, const float* __restrict__ u_all,
              const double* __restrict__ G64, const double* __restrict__ bw64,
              float* __restrict__ roi)
{
    __shared__ float  red3[3 * kP * kC];   // [(seg*256+n)*5 + c]
    __shared__ double u64s[kD];
    __shared__ double d64red[3 * kP];
    __shared__ int    bestn[kC];
    __shared__ float  gapv[kC];
    const int b = blockIdx.x, t = threadIdx.x;
    const size_t tokbase = (size_t)b * kTok;
    const int n = t & 255;
    const int seg = __builtin_amdgcn_readfirstlane(t >> 8);   // wave-uniform
    const float* __restrict__ prow = tokens + tokbase + (size_t)(kC + n) * kD + seg * 256;

    {   // fp32 sims: sim[c][n] partial over seg's 256 dims; u via uniform (scalar) loads
        const float* __restrict__ ub = u_all + (size_t)b * kC * kD + seg * 256;
        float a0 = 0, a1 = 0, a2 = 0, a3 = 0, a4 = 0;
        for (int d4 = 0; d4 < 64; ++d4) {
            const float4 p  = *(const float4*)&prow[d4 * 4];
            const float4 u0 = *(const float4*)&ub[0 * kD + d4 * 4];
            const float4 u1 = *(const float4*)&ub[1 * kD + d4 * 4];
            const float4 u2 = *(const float4*)&ub[2 * kD + d4 * 4];
            const float4 u3 = *(const float4*)&ub[3 * kD + d4 * 4];
            const float4 u4 = *(const float4*)&ub[4 * kD + d4 * 4];
            a0 += p.x * u0.x + p.y * u0.y + p.z * u0.z + p.w * u0.w;
            a1 += p.x * u1.x + p.y * u1.y + p.z * u1.z + p.w * u1.w;
            a2 += p.x * u2.x + p.y * u2.y + p.z * u2.z + p.w * u2.w;
            a3 += p.x * u3.x + p.y * u3.y + p.z * u3.z + p.w * u3.w;
            a4 += p.x * u4.x + p.y * u4.y + p.z * u4.z + p.w * u4.w;
        }
        const int base = (seg * kP + n) * kC;
        red3[base + 0] = a0; red3[base + 1] = a1; red3[base + 2] = a2;
        red3[base + 3] = a3; red3[base + 4] = a4;
    }
    __syncthreads();

    {   // top-2 per cue: one wave per cue (first-index tie-break on max)
        const int wid = t >> 6, lane = t & 63;
        if (wid < kC) {
            const int c = wid;
            float m1 = -3.4e38f, m2 = -3.4e38f; int i1 = 0;
            #pragma unroll
            for (int k = 0; k < 4; ++k) {
                const int nn = lane + k * 64;
                const float v = red3[(0 * kP + nn) * kC + c]
                              + red3[(1 * kP + nn) * kC + c]
                              + red3[(2 * kP + nn) * kC + c];
                if (v > m1 || (v == m1 && nn < i1)) { m2 = m1; m1 = v; i1 = nn; }
                else if (v > m2) m2 = v;
            }
            #pragma unroll
            for (int off = 32; off >= 1; off >>= 1) {
                const float om1 = __shfl_xor(m1, off, 64);
                const int   oi1 = __shfl_xor(i1, off, 64);
                const float om2 = __shfl_xor(m2, off, 64);
                float nm2 = fmaxf(m2, om2);
                if (om1 > m1 || (om1 == m1 && oi1 < i1)) { nm2 = fmaxf(nm2, m1); m1 = om1; i1 = oi1; }
                else nm2 = fmaxf(nm2, om1);
                m2 = nm2;
            }
            if (lane == 0) { bestn[c] = i1; gapv[c] = m1 - m2; }
        }
    }
    __syncthreads();

    // fp64 recheck of near-tie cues (block-uniform branch, rare)
    for (int c = 0; c < kC; ++c) {
        if (gapv[c] < kTau) {
            {   // u64[i] = sum_d cue[d] * G64[d][i] + bw64[i]
                const int i = t;
                double acc = bw64[i];
                for (int d = 0; d < kD; ++d) {
                    const float cf = tokens[tokbase + (size_t)c * kD + d];   // uniform
                    acc += (double)cf * G64[(size_t)d * kD + i];             // coalesced
                }
                u64s[i] = acc;
            }
            __syncthreads();
            {   // fp64 sims for this cue
                const double* __restrict__ ub = u64s + seg * 256;
                double acc = 0.0;
                for (int d4 = 0; d4 < 64; ++d4) {
                    const float4 p = *(const float4*)&prow[d4 * 4];
                    acc += (double)p.x * ub[d4 * 4 + 0] + (double)p.y * ub[d4 * 4 + 1]
                         + (double)p.z * ub[d4 * 4 + 2] + (double)p.w * ub[d4 * 4 + 3];
                }
                d64red[seg * kP + n] = acc;
            }
            __syncthreads();
            if (t < 64) {
                double best = -1.0e300; int bi = 0;
                #pragma unroll
                for (int k = 0; k < 4; ++k) {
                    const int nn = t + k * 64;
                    const double v = d64red[0 * kP + nn] + d64red[1 * kP + nn] + d64red[2 * kP + nn];
                    if (v > best || (v == best && nn < bi)) { best = v; bi = nn; }
                }
                #pragma unroll
                for (int off = 32; off >= 1; off >>= 1) {
                    const double v2 = __shfl_down(best, off, 64);
                    const int    i2 = __shfl_down(bi, off, 64);
                    if (v2 > best || (v2 == best && i2 < bi)) { best = v2; bi = i2; }
                }
                if (t == 0) bestn[c] = bi;
            }
            __syncthreads();
        }
    }

    {   // ROI means (fp32) -> roi_all
        const int d = t;
        #pragma unroll
        for (int c = 0; c < kC; ++c) {
            const int nn = bestn[c];
            const int h = nn >> 4, w = nn & 15;
            const int rlo = max(h - 1, 0), rhi = min(h + 1, kG - 1);
            const int clo = max(w - 1, 0), chi = min(w + 1, kG - 1);
            float sum = 0.0f;
            for (int rr = rlo; rr <= rhi; ++rr)
                for (int cc = clo; cc <= chi; ++cc)
                    sum += tokens[tokbase + (size_t)(kC + rr * kG + cc) * kD + d];
            roi[((size_t)b * kC + c) * kD + d] = sum / (float)((rhi - rlo + 1) * (chi - clo + 1));
        }
    }
}

// ============ K5: row-wise L2 normalize (in-place on out) ============
__global__ __launch_bounds__(256)
void k5_norm(float* __restrict__ out)
{
    __shared__ float wsum[4];
    const int row = blockIdx.x, t = threadIdx.x;
    float* p = out + (size_t)row * kD;
    const float x0 = p[t], x1 = p[t + 256], x2 = p[t + 512];
    float ss = x0 * x0 + x1 * x1 + x2 * x2;
    #pragma unroll
    for (int off = 32; off >= 1; off >>= 1) ss += __shfl_down(ss, off, 64);
    if ((t & 63) == 0) wsum[t >> 6] = ss;
    __syncthreads();
    const float tot = wsum[0] + wsum[1] + wsum[2] + wsum[3];
    const float nrm = fmaxf(sqrtf(tot), 1e-12f);
    p[t] = x0 / nrm; p[t + 256] = x1 / nrm; p[t + 512] = x2 / nrm;
}

extern "C" void kernel_launch(void* const* d_in, const int* in_sizes, int n_in,
                              void* d_out, int out_size, void* d_ws, size_t ws_size,
                              hipStream_t stream) {
    const float* tokens = (const float*)d_in[0];
    const float* W      = (const float*)d_in[1];
    const float* bvec   = (const float*)d_in[2];
    float* out = (float*)d_out;
    char* ws = (char*)d_ws;
    double* G64  = (double*)(ws);
    double* bw64 = (double*)(ws + 4718592);
    float*  G32  = (float*) (ws + 4724736);
    float*  bw32 = (float*) (ws + 7084032);
    float*  u_all= (float*) (ws + 7087104);
    float*  roi  = (float*) (ws + 11019264);

    k1_gram<<<dim3(579), dim3(256), 0, stream>>>(W, bvec, G64, G32, bw64, bw32);
    k2_gemm<<<dim3(20, 48), dim3(256), 0, stream>>>(0, tokens, W, G32, bvec, bw32, roi, u_all, out);
    k3_batch<<<dim3(256), dim3(768), 0, stream>>>(tokens, u_all, G64, bw64, roi);
    k2_gemm<<<dim3(20, 24), dim3(256), 0, stream>>>(1, tokens, W, G32, bvec, bw32, roi, u_all, out);
    k5_norm<<<dim3(2560), dim3(256), 0, stream>>>(out);
}

// Round 4
// 247.191 us; speedup vs baseline: 1.2140x; 1.2140x over previous
//
#include <hip/hip_runtime.h>
#include <math.h>

constexpr int kB = 256;      // batches
constexpr int kT = 261;      // tokens per batch
constexpr int kD = 768;      // dim
constexpr int kC = 5;        // cue tokens
constexpr int kG = 16;       // patch grid
constexpr int kP = 256;      // patches per batch
constexpr int kTok = kT * kD;
constexpr float kTau = 0.03f;   // fp32 screening gap threshold

// ---------------- ws layout (floats) ----------------
// tcb   : 1280*768 @ 0          (cue projections, fp32)
// u_all : 1280*768 @ 983040     (screen vectors u = tcb*W)
// roi   : 1280*768 @ 1966080    (raw ROI means)
// sims  : 1280*256 @ 2949120    (fp32 screen sims, [b*1280 + c*256 + n])
// total 13.1 MB

// ============ GEMM: C(1280x768) = A(1280x768) * B + optional bias ============
// MODE 0: A = cue rows gathered from tokens, B = W^T, +bias -> dstA=tcb, dstB=out rows c
// MODE 1: A = tcb (dense),                   B = W,    no bias -> dstA=u_all
// MODE 2: A = roi (dense),                   B = W^T, +bias -> dstA=out rows 5+c
template<int MODE>
__global__ __launch_bounds__(256)
void gemm_k(const float* __restrict__ tokens, const float* __restrict__ W,
            const float* __restrict__ bvec, const float* __restrict__ Asrc,
            float* __restrict__ dstA, float* __restrict__ dstB)
{
    __shared__ float As[32][68];   // [k][m], stride 68 (16B-aligned rows)
    __shared__ float Bs[32][68];   // [k][n]
    const int mt = blockIdx.x, nt = blockIdx.y;
    const int t = threadIdx.x;
    const int tx = t & 15, ty = t >> 4;
    const int sr = t >> 2, sq = t & 3;       // transpose-staging: row(64), 8-float group
    const int brow = t >> 3, bq = t & 7;     // direct-staging: k-row(32), 8-float group

    const int am = mt * 64 + sr;
    const float* __restrict__ Ap = (MODE == 0) ? tokens : Asrc;
    const size_t arow = (MODE == 0)
        ? ((size_t)(am / 5) * kTok + (size_t)(am % 5) * kD)
        : ((size_t)am * kD);

    float4 pa0, pa1, pb0, pb1;
    auto load_regs = [&](int kc) {
        pa0 = *(const float4*)&Ap[arow + kc + sq * 8];
        pa1 = *(const float4*)&Ap[arow + kc + sq * 8 + 4];
        if (MODE == 1) {
            pb0 = *(const float4*)&W[(size_t)(kc + brow) * kD + nt * 64 + bq * 8];
            pb1 = *(const float4*)&W[(size_t)(kc + brow) * kD + nt * 64 + bq * 8 + 4];
        } else {
            pb0 = *(const float4*)&W[(size_t)(nt * 64 + sr) * kD + kc + sq * 8];
            pb1 = *(const float4*)&W[(size_t)(nt * 64 + sr) * kD + kc + sq * 8 + 4];
        }
    };
    auto write_lds = [&]() {
        As[sq*8+0][sr] = pa0.x; As[sq*8+1][sr] = pa0.y; As[sq*8+2][sr] = pa0.z; As[sq*8+3][sr] = pa0.w;
        As[sq*8+4][sr] = pa1.x; As[sq*8+5][sr] = pa1.y; As[sq*8+6][sr] = pa1.z; As[sq*8+7][sr] = pa1.w;
        if (MODE == 1) {
            *(float4*)&Bs[brow][bq*8]     = pb0;
            *(float4*)&Bs[brow][bq*8 + 4] = pb1;
        } else {
            Bs[sq*8+0][sr] = pb0.x; Bs[sq*8+1][sr] = pb0.y; Bs[sq*8+2][sr] = pb0.z; Bs[sq*8+3][sr] = pb0.w;
            Bs[sq*8+4][sr] = pb1.x; Bs[sq*8+5][sr] = pb1.y; Bs[sq*8+6][sr] = pb1.z; Bs[sq*8+7][sr] = pb1.w;
        }
    };

    float acc[4][4] = {};
    auto compute = [&]() {
        #pragma unroll
        for (int kk = 0; kk < 32; ++kk) {
            const float4 a  = *(const float4*)&As[kk][ty * 4];   // 4-addr broadcast
            const float4 bb = *(const float4*)&Bs[kk][tx * 4];
            acc[0][0] += a.x*bb.x; acc[0][1] += a.x*bb.y; acc[0][2] += a.x*bb.z; acc[0][3] += a.x*bb.w;
            acc[1][0] += a.y*bb.x; acc[1][1] += a.y*bb.y; acc[1][2] += a.y*bb.z; acc[1][3] += a.y*bb.w;
            acc[2][0] += a.z*bb.x; acc[2][1] += a.z*bb.y; acc[2][2] += a.z*bb.z; acc[2][3] += a.z*bb.w;
            acc[3][0] += a.w*bb.x; acc[3][1] += a.w*bb.y; acc[3][2] += a.w*bb.z; acc[3][3] += a.w*bb.w;
        }
    };

    load_regs(0);
    write_lds();
    __syncthreads();
    for (int kc = 32; kc < kD; kc += 32) {
        load_regs(kc);          // prefetch next chunk under compute
        compute();
        __syncthreads();
        write_lds();
        __syncthreads();
    }
    compute();

    const int n0 = nt * 64 + tx * 4;
    float4 bv = make_float4(0.f, 0.f, 0.f, 0.f);
    if (MODE != 1) bv = *(const float4*)&bvec[n0];
    #pragma unroll
    for (int mi = 0; mi < 4; ++mi) {
        const int m = mt * 64 + ty * 4 + mi;
        const float4 r = make_float4(acc[mi][0] + bv.x, acc[mi][1] + bv.y,
                                     acc[mi][2] + bv.z, acc[mi][3] + bv.w);
        if (MODE == 0) {
            *(float4*)&dstA[(size_t)m * kD + n0] = r;
            *(float4*)&dstB[((size_t)(m / 5) * 10 + (m % 5)) * kD + n0] = r;
        } else if (MODE == 1) {
            *(float4*)&dstA[(size_t)m * kD + n0] = r;
        } else {
            *(float4*)&dstA[((size_t)(m / 5) * 10 + 5 + (m % 5)) * kD + n0] = r;
        }
    }
}

// ============ K3a: fp32 screen sims, wave-per-patch (coalesced) ============
__global__ __launch_bounds__(512, 4)
void k3a_sims(const float* __restrict__ tokens, const float* __restrict__ u_all,
              float* __restrict__ sims)
{
    const int blk = blockIdx.x;
    const int b = blk >> 1, half = blk & 1;
    const int t = threadIdx.x;
    const int w = t >> 6, lane = t & 63;
    const size_t tb = (size_t)b * kTok;

    float4 u[kC][3];   // per-lane u fragments (12 floats per cue)
    {
        const float* ub = u_all + (size_t)b * kC * kD + lane * 4;
        #pragma unroll
        for (int c = 0; c < kC; ++c)
            #pragma unroll
            for (int k = 0; k < 3; ++k)
                u[c][k] = *(const float4*)&ub[c * kD + k * 256];
    }
    const int n0 = half * 128 + w * 16;
    for (int i = 0; i < 16; ++i) {
        const int n = n0 + i;
        const float* p = &tokens[tb + (size_t)(kC + n) * kD + lane * 4];
        const float4 p0 = *(const float4*)&p[0];     // wave reads contiguous 1KB
        const float4 p1 = *(const float4*)&p[256];
        const float4 p2 = *(const float4*)&p[512];
        float s[kC];
        #pragma unroll
        for (int c = 0; c < kC; ++c) {
            s[c] = p0.x*u[c][0].x + p0.y*u[c][0].y + p0.z*u[c][0].z + p0.w*u[c][0].w
                 + p1.x*u[c][1].x + p1.y*u[c][1].y + p1.z*u[c][1].z + p1.w*u[c][1].w
                 + p2.x*u[c][2].x + p2.y*u[c][2].y + p2.z*u[c][2].z + p2.w*u[c][2].w;
        }
        #pragma unroll
        for (int off = 32; off >= 1; off >>= 1)
            #pragma unroll
            for (int c = 0; c < kC; ++c)
                s[c] += __shfl_xor(s[c], off, 64);
        float v = s[4];
        if (lane == 0) v = s[0]; else if (lane == 1) v = s[1];
        else if (lane == 2) v = s[2]; else if (lane == 3) v = s[3];
        if (lane < kC)
            sims[(size_t)b * (kC * kP) + lane * kP + n] = v;
    }
}

// ============ K3b: top-2 + rare fp64 recheck + ROI means ============
__global__ __launch_bounds__(768, 1)
void k3b_select(const float* __restrict__ tokens, const float* __restrict__ W,
                const float* __restrict__ bvec, const float* __restrict__ sims,
                float* __restrict__ roi)
{
    __shared__ double tcb64[kD];
    __shared__ double u64s[kD];
    __shared__ double s64[kP];
    __shared__ int bestn[kC];
    __shared__ int flags;
    const int b = blockIdx.x, t = threadIdx.x;
    const int w = t >> 6, lane = t & 63;
    const size_t tb = (size_t)b * kTok;

    if (t == 0) flags = 0;
    __syncthreads();

    if (w < kC) {     // top-2 per cue, one wave per cue
        const int c = w;
        const float* sr_ = &sims[(size_t)b * (kC * kP) + c * kP];
        float m1 = -3.4e38f, m2 = -3.4e38f; int i1 = 0;
        #pragma unroll
        for (int k = 0; k < 4; ++k) {
            const int n = lane + k * 64;
            const float v = sr_[n];
            if (v > m1 || (v == m1 && n < i1)) { m2 = m1; m1 = v; i1 = n; }
            else if (v > m2) m2 = v;
        }
        #pragma unroll
        for (int off = 32; off >= 1; off >>= 1) {
            const float om1 = __shfl_xor(m1, off, 64);
            const int   oi1 = __shfl_xor(i1, off, 64);
            const float om2 = __shfl_xor(m2, off, 64);
            float nm2 = fmaxf(m2, om2);
            if (om1 > m1 || (om1 == m1 && oi1 < i1)) { nm2 = fmaxf(nm2, m1); m1 = om1; i1 = oi1; }
            else nm2 = fmaxf(nm2, om1);
            m2 = nm2;
        }
        if (lane == 0) {
            bestn[c] = i1;
            if (m1 - m2 < kTau) atomicOr(&flags, 1 << c);
        }
    }
    __syncthreads();

    // fp64 recheck for flagged cues (block-uniform, expected ~3% of cues)
    for (int c = 0; c < kC; ++c) {
        if (!(flags & (1 << c))) continue;
        {   // tcb64[j] = cue . W[j] + b[j], wave-per-row (coalesced W reads)
            const float* cuep = &tokens[tb + (size_t)c * kD + lane * 4];
            const float4 cf0 = *(const float4*)&cuep[0];
            const float4 cf1 = *(const float4*)&cuep[256];
            const float4 cf2 = *(const float4*)&cuep[512];
            for (int j = w; j < kD; j += 12) {
                const float* wr = &W[(size_t)j * kD + lane * 4];
                const float4 w0 = *(const float4*)&wr[0];
                const float4 w1 = *(const float4*)&wr[256];
                const float4 w2 = *(const float4*)&wr[512];
                double acc = (double)w0.x*cf0.x + (double)w0.y*cf0.y + (double)w0.z*cf0.z + (double)w0.w*cf0.w
                           + (double)w1.x*cf1.x + (double)w1.y*cf1.y + (double)w1.z*cf1.z + (double)w1.w*cf1.w
                           + (double)w2.x*cf2.x + (double)w2.y*cf2.y + (double)w2.z*cf2.z + (double)w2.w*cf2.w;
                #pragma unroll
                for (int off = 32; off >= 1; off >>= 1)
                    acc += __shfl_xor(acc, off, 64);
                if (lane == 0) tcb64[j] = acc + (double)bvec[j];
            }
        }
        __syncthreads();
        {   // u64[i] = sum_j tcb64[j] * W[j][i]  (coalesced over i)
            double acc = 0.0;
            for (int j = 0; j < kD; ++j)
                acc += tcb64[j] * (double)W[(size_t)j * kD + t];
            u64s[t] = acc;
        }
        __syncthreads();
        {   // fp64 sims, wave-per-patch
            for (int n = w; n < kP; n += 12) {
                const float* p = &tokens[tb + (size_t)(kC + n) * kD + lane * 4];
                const float4 p0 = *(const float4*)&p[0];
                const float4 p1 = *(const float4*)&p[256];
                const float4 p2 = *(const float4*)&p[512];
                const double* ud = &u64s[lane * 4];
                double acc = (double)p0.x*ud[0]   + (double)p0.y*ud[1]   + (double)p0.z*ud[2]   + (double)p0.w*ud[3]
                           + (double)p1.x*ud[256] + (double)p1.y*ud[257] + (double)p1.z*ud[258] + (double)p1.w*ud[259]
                           + (double)p2.x*ud[512] + (double)p2.y*ud[513] + (double)p2.z*ud[514] + (double)p2.w*ud[515];
                #pragma unroll
                for (int off = 32; off >= 1; off >>= 1)
                    acc += __shfl_xor(acc, off, 64);
                if (lane == 0) s64[n] = acc;
            }
        }
        __syncthreads();
        if (w == 0) {   // fp64 argmax, first-index tie-break
            double best = -1.0e300; int bi = 0;
            #pragma unroll
            for (int k = 0; k < 4; ++k) {
                const int n = lane + k * 64;
                const double v = s64[n];
                if (v > best || (v == best && n < bi)) { best = v; bi = n; }
            }
            #pragma unroll
            for (int off = 32; off >= 1; off >>= 1) {
                const double v2 = __shfl_xor(best, off, 64);
                const int    i2 = __shfl_xor(bi, off, 64);
                if (v2 > best || (v2 == best && i2 < bi)) { best = v2; bi = i2; }
            }
            if (lane == 0) bestn[c] = bi;
        }
        __syncthreads();
    }

    {   // ROI means (coalesced over d = t)
        const int d = t;
        #pragma unroll
        for (int c = 0; c < kC; ++c) {
            const int nn = bestn[c];
            const int h = nn >> 4, ww = nn & 15;
            const int rlo = max(h - 1, 0), rhi = min(h + 1, kG - 1);
            const int clo = max(ww - 1, 0), chi = min(ww + 1, kG - 1);
            float sum = 0.f;
            for (int rr = rlo; rr <= rhi; ++rr)
                for (int cc = clo; cc <= chi; ++cc)
                    sum += tokens[tb + (size_t)(kC + rr * kG + cc) * kD + d];
            roi[((size_t)b * kC + c) * kD + d] = sum / (float)((rhi - rlo + 1) * (chi - clo + 1));
        }
    }
}

// ============ K5: row-wise L2 normalize (in-place on out) ============
__global__ __launch_bounds__(256)
void k5_norm(float* __restrict__ out)
{
    __shared__ float wsum[4];
    const int row = blockIdx.x, t = threadIdx.x;
    float* p = out + (size_t)row * kD;
    const float x0 = p[t], x1 = p[t + 256], x2 = p[t + 512];
    float ss = x0 * x0 + x1 * x1 + x2 * x2;
    #pragma unroll
    for (int off = 32; off >= 1; off >>= 1) ss += __shfl_down(ss, off, 64);
    if ((t & 63) == 0) wsum[t >> 6] = ss;
    __syncthreads();
    const float tot = wsum[0] + wsum[1] + wsum[2] + wsum[3];
    const float nrm = fmaxf(sqrtf(tot), 1e-12f);
    p[t] = x0 / nrm; p[t + 256] = x1 / nrm; p[t + 512] = x2 / nrm;
}

extern "C" void kernel_launch(void* const* d_in, const int* in_sizes, int n_in,
                              void* d_out, int out_size, void* d_ws, size_t ws_size,
                              hipStream_t stream) {
    const float* tokens = (const float*)d_in[0];
    const float* W      = (const float*)d_in[1];
    const float* bvec   = (const float*)d_in[2];
    float* out = (float*)d_out;
    float* ws = (float*)d_ws;
    float* tcb   = ws;
    float* u_all = ws + 983040;
    float* roi   = ws + 1966080;
    float* sims  = ws + 2949120;

    gemm_k<0><<<dim3(20, 12), 256, 0, stream>>>(tokens, W, bvec, nullptr, tcb, out);
    gemm_k<1><<<dim3(20, 12), 256, 0, stream>>>(tokens, W, bvec, tcb, u_all, nullptr);
    k3a_sims<<<dim3(512), 512, 0, stream>>>(tokens, u_all, sims);
    k3b_select<<<dim3(256), 768, 0, stream>>>(tokens, W, bvec, sims, roi);
    gemm_k<2><<<dim3(20, 12), 256, 0, stream>>>(tokens, W, bvec, roi, out, nullptr);
    k5_norm<<<dim3(2560), 256, 0, stream>>>(out);
}